// Round 11
// baseline (86.672 us; speedup 1.0000x reference)
//
#include <hip/hip_runtime.h>
#include <hip/hip_bf16.h>

typedef __attribute__((ext_vector_type(8)))  __bf16 bf16x8;
typedef __attribute__((ext_vector_type(4)))  __bf16 bf16x4;
typedef __attribute__((ext_vector_type(2)))  __bf16 bf16x2;
typedef __attribute__((ext_vector_type(4)))  float  f32x4;
typedef __attribute__((ext_vector_type(16))) float  f32x16;

#define MFMA16(a,b,c) __builtin_amdgcn_mfma_f32_16x16x32_bf16((a),(b),(c),0,0,0)
#define MFMA32(a,b,c) __builtin_amdgcn_mfma_f32_32x32x16_bf16((a),(b),(c),0,0,0)

__device__ inline void gload_lds16(const __bf16* g, __bf16* l) {
  __builtin_amdgcn_global_load_lds(
      (const __attribute__((address_space(1))) void*)g,
      (__attribute__((address_space(3))) void*)l, 16, 0, 0);
}

// ---------------------------------------------------------------------------
// Projection GEMM, f32 inputs with FUSED bf16 conversion in reg-staging.
// z=0: Q scaled by log2e/sqrt(128), masked rows zeroed -> [bh][s][128].
// z=1: K FRAGMENT-LINEAR per bh: element (kv=s, d) at
//      idx = ((t*2+kw)*8 + ds)*512 + hi3*256 + r5*8 + j
//      (t=s>>6, kw=s[5], r5=s&31, ds=d>>4, hi3=d[3], j=d&7)
// z=2: V FRAGMENT-LINEAR per bh: element (d, kv=s) at
//      idx = ((t*2+kw)*8 + dblk*2+s2)*512 + hi3*256 + r5*8 + j
//      (t=s>>6, kw=s[5], s2=s[4], hi3=s[3], j=s&7, dblk=d>>5, r5=d&31)
// Both give attn lane-contiguous 1KB wave loads (512 elems/unit).
// ---------------------------------------------------------------------------
__global__ __launch_bounds__(256, 2) void gemm_kernel(
    const float* __restrict__ Xq, const float* __restrict__ Xk,
    const float* __restrict__ Xv, const float* __restrict__ Wq,
    const float* __restrict__ Wk, const float* __restrict__ Wv,
    const float* __restrict__ bq, const float* __restrict__ bk,
    const float* __restrict__ bv, const int* __restrict__ mask,
    __bf16* __restrict__ dq, __bf16* __restrict__ dk, __bf16* __restrict__ dv)
{
  const int which = blockIdx.z;
  const float* X    = which == 0 ? Xq : which == 1 ? Xk : Xv;
  const float* W    = which == 0 ? Wq : which == 1 ? Wk : Wv;
  const float* bias = which == 0 ? bq : which == 1 ? bk : bv;
  __bf16* dst       = which == 0 ? dq : which == 1 ? dk : dv;
  const float oscale = which == 0 ? 0.12751744710339033f : 1.0f; // log2e/sqrt(128)

  // [128][64] bf16, 16B slot s stored at s^(row&7)
  __shared__ __align__(16) __bf16 Al[2][128 * 64];
  __shared__ __align__(16) __bf16 Bl[2][128 * 64];

  const int tid  = threadIdx.x;
  const int lane = tid & 63;
  const int w    = tid >> 6;
  const int wr = w >> 1, wc = w & 1;
  const int mbase = blockIdx.x * 128;
  const int nbase = blockIdx.y * 128;
  const int arow = lane & 15;
  const int hi   = lane >> 4;

  f32x4 acc[4][4] = {};
  float4 ar[8], br[8];

  auto issue = [&](int k0) {
#pragma unroll
    for (int i = 0; i < 8; ++i) {
      int idx = tid + i * 256;
      int r = idx >> 4, c = (idx & 15) * 4;
      ar[i] = *(const float4*)&X[(size_t)(mbase + r) * 512 + k0 + c];
      br[i] = *(const float4*)&W[(size_t)(nbase + r) * 512 + k0 + c];
    }
  };
  auto commit = [&](int buf) {
#pragma unroll
    for (int i = 0; i < 8; ++i) {
      int idx = tid + i * 256;
      int r = idx >> 4, c4 = idx & 15;
      int slot = c4 >> 1, half = c4 & 1;
      int addr = r * 64 + (slot ^ (r & 7)) * 8 + half * 4;
      bf16x4 av, bv2;
      av[0] = (__bf16)ar[i].x; av[1] = (__bf16)ar[i].y;
      av[2] = (__bf16)ar[i].z; av[3] = (__bf16)ar[i].w;
      bv2[0] = (__bf16)br[i].x; bv2[1] = (__bf16)br[i].y;
      bv2[2] = (__bf16)br[i].z; bv2[3] = (__bf16)br[i].w;
      *(bf16x4*)&Al[buf][addr] = av;
      *(bf16x4*)&Bl[buf][addr] = bv2;
    }
  };

  issue(0);
  commit(0);

  for (int t = 0; t < 8; ++t) {
    const int cur = t & 1;
    if (t < 7) issue((t + 1) * 64);
    __syncthreads();

    __builtin_amdgcn_s_setprio(1);
#pragma unroll
    for (int kk = 0; kk < 2; ++kk) {
      bf16x8 af[4], bfr[4];
#pragma unroll
      for (int m = 0; m < 4; ++m) {
        int row = wr * 64 + m * 16 + arow;
        int sl  = ((kk * 4 + hi) ^ (row & 7)) * 8;
        af[m] = *(bf16x8*)&Al[cur][row * 64 + sl];
      }
#pragma unroll
      for (int n = 0; n < 4; ++n) {
        int row = wc * 64 + n * 16 + arow;
        int sl  = ((kk * 4 + hi) ^ (row & 7)) * 8;
        bfr[n] = *(bf16x8*)&Bl[cur][row * 64 + sl];
      }
#pragma unroll
      for (int m = 0; m < 4; ++m)
#pragma unroll
        for (int n = 0; n < 4; ++n)
          acc[m][n] = MFMA16(af[m], bfr[n], acc[m][n]);
    }
    __builtin_amdgcn_s_setprio(0);

    if (t < 7) commit(cur ^ 1);
  }

  // Epilogue: bias + relu + oscale (+ Q row-mask zeroing), bf16 store.
#pragma unroll
  for (int n = 0; n < 4; ++n) {
    int col = nbase + wc * 64 + n * 16 + arow;
    float bsv = bias[col];
    int h = col >> 7, d = col & 127;
#pragma unroll
    for (int m = 0; m < 4; ++m) {
      int row0 = mbase + wr * 64 + m * 16 + hi * 4;
#pragma unroll
      for (int r = 0; r < 4; ++r) {
        float v = acc[m][n][r] + bsv;
        v = (v > 0.0f ? v : 0.0f) * oscale;
        int mm = row0 + r;
        int b = mm >> 11, s = mm & 2047;
        if (which == 0 && mask[b * 2048 + s] != 0) v = 0.0f;
        size_t bhoff = (size_t)(b * 4 + h) * (2048 * 128);
        int tt = s >> 6, kw_ = (s >> 5) & 1;
        if (which == 0) {
          dst[bhoff + (size_t)s * 128 + d] = (__bf16)v;
        } else if (which == 1) {
          // K fragment-linear
          int r5k = s & 31;
          int ds = d >> 4, hi3 = (d >> 3) & 1, j = d & 7;
          size_t unit = ((size_t)tt * 2 + kw_) * 8 + ds;
          dst[bhoff + unit * 512 + hi3 * 256 + r5k * 8 + j] = (__bf16)v;
        } else {
          // V fragment-linear
          int s2 = (s >> 4) & 1, hi3 = (s >> 3) & 1, j = s & 7;
          int dblk = d >> 5, r5 = d & 31;
          size_t unit = ((size_t)tt * 2 + kw_) * 8 + dblk * 2 + s2;
          dst[bhoff + unit * 512 + hi3 * 256 + r5 * 8 + j] = (__bf16)v;
        }
      }
    }
  }
}

// ---------------------------------------------------------------------------
// Flash attention, BARRIER-FREE main loop: K and V both fragment-linear in
// global (all loads lane-contiguous 1KB, L2-served), all compute in registers.
// 128 thr = 2 independent waves (kv-halves); software pipeline: K(t+1) after
// QK(t), V double-buffered 2 tiles ahead. Single merge via LDS at the end.
// grid 1024 = 8 XCD x (2 bh x 64 q-tiles of 32 rows).
// ---------------------------------------------------------------------------
__global__ __launch_bounds__(128, 2) void attn_kernel(
    const __bf16* __restrict__ qh, const __bf16* __restrict__ kfr,
    const __bf16* __restrict__ vfr, const float* __restrict__ queries,
    float* __restrict__ out)
{
  __shared__ float Ll[32];
  __shared__ __align__(16) float Ob[64 * 68];

  const int tid  = threadIdx.x;
  const int lane = tid & 63;
  const int kw   = tid >> 6;        // kv-half
  const int r5   = lane & 31;
  const int hi32 = lane >> 5;

  const int blk  = blockIdx.x;      // 0..1023
  const int xcd  = blk & 7;
  const int rest = blk >> 3;        // 0..127
  const int bh   = xcd * 2 + (rest & 1);
  const int qt   = rest >> 1;       // 0..63
  const int b = bh >> 2, h = bh & 3;
  const int qbase = qt * 32;

  const __bf16* qptr = qh  + (size_t)bh * 2048 * 128;
  const __bf16* kp   = kfr + (size_t)bh * 2048 * 128;
  const __bf16* vp   = vfr + (size_t)bh * 2048 * 128;

  bf16x8 qf[8];
#pragma unroll
  for (int ds = 0; ds < 8; ++ds)
    qf[ds] = *(const bf16x8*)&qptr[(size_t)(qbase + r5) * 128 + ds * 16 + hi32 * 8];

  float l_st = 0.f;
  f32x16 oacc[4] = {};
  bf16x8 kf[8], vfA[8], vfB[8];

  auto loadK = [&](int t) {
#pragma unroll
    for (int ds = 0; ds < 8; ++ds)
      kf[ds] = *(const bf16x8*)
          &kp[(((size_t)t * 2 + kw) * 8 + ds) * 512 + lane * 8];
  };
  auto loadV = [&](bf16x8 (&dstv)[8], int t) {
#pragma unroll
    for (int u = 0; u < 8; ++u)
      dstv[u] = *(const bf16x8*)
          &vp[(((size_t)t * 2 + kw) * 8 + u) * 512 + lane * 8];
  };

  auto body = [&](int t, bf16x8 (&vcur)[8]) {
    // QK^T swapped: S[kv][q=lane&31] (log2 domain, Q pre-scaled).
    f32x16 sacc = {};
    __builtin_amdgcn_s_setprio(1);
#pragma unroll
    for (int ds = 0; ds < 8; ++ds)
      sacc = MFMA32(kf[ds], qf[ds], sacc);
    __builtin_amdgcn_s_setprio(0);

    if (t + 1 < 32) loadK(t + 1);   // K prefetch: lands during softmax+PV

    // Fixed-reference softmax: P = exp2(s) (scores >= 0, bounded; masked
    // rows have Q==0 -> P==1 -> mean(V)). Tree-sum.
    float ps[16];
#pragma unroll
    for (int r = 0; r < 16; ++r) {
      ps[r] = __builtin_amdgcn_exp2f(sacc[r]);
      sacc[r] = ps[r];
    }
#pragma unroll
    for (int st = 1; st < 16; st <<= 1)
#pragma unroll
      for (int r = 0; r < 16; r += 2 * st)
        ps[r] += ps[r + st];
    l_st += ps[0];

    // P -> B-frags: bf16 pack pairs + permlane32_swap.
    unsigned pk[8];
#pragma unroll
    for (int g = 0; g < 8; ++g) {
      bf16x2 tp;
      tp[0] = (__bf16)sacc[2 * g];
      tp[1] = (__bf16)sacc[2 * g + 1];
      pk[g] = __builtin_bit_cast(unsigned, tp);
    }
    bf16x8 pf[2];
#pragma unroll
    for (int s = 0; s < 2; ++s) {
      unsigned a0 = pk[4 * s + 0], a1 = pk[4 * s + 1];
      unsigned b0 = pk[4 * s + 2], b1 = pk[4 * s + 3];
      asm("v_permlane32_swap_b32 %0, %1" : "+v"(a0), "+v"(b0));
      asm("v_permlane32_swap_b32 %0, %1" : "+v"(a1), "+v"(b1));
      union { unsigned u[4]; bf16x8 v; } pu;
      pu.u[0] = a0; pu.u[1] = a1; pu.u[2] = b0; pu.u[3] = b1;
      pf[s] = pu.v;
    }

    __builtin_amdgcn_s_setprio(1);
#pragma unroll
    for (int u = 0; u < 8; ++u)     // u = dblk*2 + s
      oacc[u >> 1] = MFMA32(vcur[u], pf[u & 1], oacc[u >> 1]);
    __builtin_amdgcn_s_setprio(0);

    if (t + 2 < 32) loadV(vcur, t + 2);  // V prefetch, 2 tiles ahead
  };

  loadK(0);
  loadV(vfA, 0);
  loadV(vfB, 1);

  for (int tt = 0; tt < 16; ++tt) {
    body(2 * tt, vfA);
    body(2 * tt + 1, vfB);
  }

  // ---- merge kv-halves (l and O are plain sums), then epilogue ----
  float l_tot = l_st + __shfl_xor(l_st, 32);

  if (kw == 1) {
    if (hi32 == 0) Ll[r5] = l_tot;
    float* dstp = Ob + (size_t)lane * 68;
#pragma unroll
    for (int dblk = 0; dblk < 4; ++dblk)
      *(f32x16*)(dstp + dblk * 16) = oacc[dblk];
  }
  __syncthreads();

  if (kw == 0) {
    float l1 = Ll[r5];
    float inv = 1.0f / (l_tot + l1);
    const float* src = Ob + (size_t)lane * 68;

    const int qhi = qt >> 4;
    const int col = (qt & 15) * 32 + r5;
#pragma unroll
    for (int dblk = 0; dblk < 4; ++dblk) {
      f32x16 o1 = *(const f32x16*)(src + dblk * 16);
#pragma unroll
      for (int r = 0; r < 16; ++r) {
        int d = dblk * 32 + (r & 3) + 8 * (r >> 2) + 4 * hi32;
        int srow = h * 512 + d * 4 + qhi;
        size_t o = ((size_t)b * 2048 + srow) * 512 + col;
        out[o] = (oacc[dblk][r] + o1[r]) * inv + queries[o];
      }
    }
  }
}

extern "C" void kernel_launch(void* const* d_in, const int* in_sizes, int n_in,
                              void* d_out, int out_size, void* d_ws, size_t ws_size,
                              hipStream_t stream) {
  const float* queries = (const float*)d_in[0];
  const float* keys    = (const float*)d_in[1];
  const float* values  = (const float*)d_in[2];
  const int*   mask    = (const int*)d_in[3];
  const float* Wq = (const float*)d_in[4];
  const float* bq = (const float*)d_in[5];
  const float* Wk = (const float*)d_in[6];
  const float* bk = (const float*)d_in[7];
  const float* Wv = (const float*)d_in[8];
  const float* bv = (const float*)d_in[9];
  float* out = (float*)d_out;

  const size_t perX = (size_t)8192 * 512;
  __bf16* qhp = (__bf16*)d_ws;
  __bf16* khp = qhp + perX;
  __bf16* vtp = khp + perX;

  gemm_kernel<<<dim3(64, 4, 3), dim3(256), 0, stream>>>(
      queries, keys, values, Wq, Wk, Wv, bq, bk, bv, mask, qhp, khp, vtp);

  attn_kernel<<<dim3(1024), dim3(128), 0, stream>>>(qhp, khp, vtp, queries, out);
}

// Round 12
// 86.591 us; speedup vs baseline: 1.0009x; 1.0009x over previous
//
#include <hip/hip_runtime.h>
#include <hip/hip_bf16.h>

typedef __attribute__((ext_vector_type(8)))  __bf16 bf16x8;
typedef __attribute__((ext_vector_type(4)))  __bf16 bf16x4;
typedef __attribute__((ext_vector_type(2)))  __bf16 bf16x2;
typedef __attribute__((ext_vector_type(4)))  float  f32x4;
typedef __attribute__((ext_vector_type(16))) float  f32x16;

#define MFMA16(a,b,c) __builtin_amdgcn_mfma_f32_16x16x32_bf16((a),(b),(c),0,0,0)
#define MFMA32(a,b,c) __builtin_amdgcn_mfma_f32_32x32x16_bf16((a),(b),(c),0,0,0)

// ---------------------------------------------------------------------------
// Projection GEMM, f32 inputs with FUSED bf16 conversion in reg-staging.
// z=0: Q scaled by log2e/sqrt(128), masked rows zeroed -> [bh][s][128].
// z=1: K FRAGMENT-LINEAR per bh (unit=((t*2+kw)*8+ds), elem hi3*256+r5*8+j).
// z=2: V FRAGMENT-LINEAR per bh (unit=((t*2+kw)*8+dblk*2+s2)).
// Both give attn lane-contiguous 1KB wave loads (512 elems/unit).
// ---------------------------------------------------------------------------
__global__ __launch_bounds__(256, 2) void gemm_kernel(
    const float* __restrict__ Xq, const float* __restrict__ Xk,
    const float* __restrict__ Xv, const float* __restrict__ Wq,
    const float* __restrict__ Wk, const float* __restrict__ Wv,
    const float* __restrict__ bq, const float* __restrict__ bk,
    const float* __restrict__ bv, const int* __restrict__ mask,
    __bf16* __restrict__ dq, __bf16* __restrict__ dk, __bf16* __restrict__ dv)
{
  const int which = blockIdx.z;
  const float* X    = which == 0 ? Xq : which == 1 ? Xk : Xv;
  const float* W    = which == 0 ? Wq : which == 1 ? Wk : Wv;
  const float* bias = which == 0 ? bq : which == 1 ? bk : bv;
  __bf16* dst       = which == 0 ? dq : which == 1 ? dk : dv;
  const float oscale = which == 0 ? 0.12751744710339033f : 1.0f; // log2e/sqrt(128)

  // [128][64] bf16, 16B slot s stored at s^(row&7)
  __shared__ __align__(16) __bf16 Al[2][128 * 64];
  __shared__ __align__(16) __bf16 Bl[2][128 * 64];

  const int tid  = threadIdx.x;
  const int lane = tid & 63;
  const int w    = tid >> 6;
  const int wr = w >> 1, wc = w & 1;
  const int mbase = blockIdx.x * 128;
  const int nbase = blockIdx.y * 128;
  const int arow = lane & 15;
  const int hi   = lane >> 4;

  f32x4 acc[4][4] = {};
  float4 ar[8], br[8];

  auto issue = [&](int k0) {
#pragma unroll
    for (int i = 0; i < 8; ++i) {
      int idx = tid + i * 256;
      int r = idx >> 4, c = (idx & 15) * 4;
      ar[i] = *(const float4*)&X[(size_t)(mbase + r) * 512 + k0 + c];
      br[i] = *(const float4*)&W[(size_t)(nbase + r) * 512 + k0 + c];
    }
  };
  auto commit = [&](int buf) {
#pragma unroll
    for (int i = 0; i < 8; ++i) {
      int idx = tid + i * 256;
      int r = idx >> 4, c4 = idx & 15;
      int slot = c4 >> 1, half = c4 & 1;
      int addr = r * 64 + (slot ^ (r & 7)) * 8 + half * 4;
      bf16x4 av, bv2;
      av[0] = (__bf16)ar[i].x; av[1] = (__bf16)ar[i].y;
      av[2] = (__bf16)ar[i].z; av[3] = (__bf16)ar[i].w;
      bv2[0] = (__bf16)br[i].x; bv2[1] = (__bf16)br[i].y;
      bv2[2] = (__bf16)br[i].z; bv2[3] = (__bf16)br[i].w;
      *(bf16x4*)&Al[buf][addr] = av;
      *(bf16x4*)&Bl[buf][addr] = bv2;
    }
  };

  issue(0);
  commit(0);

  for (int t = 0; t < 8; ++t) {
    const int cur = t & 1;
    if (t < 7) issue((t + 1) * 64);
    __syncthreads();

    __builtin_amdgcn_s_setprio(1);
#pragma unroll
    for (int kk = 0; kk < 2; ++kk) {
      bf16x8 af[4], bfr[4];
#pragma unroll
      for (int m = 0; m < 4; ++m) {
        int row = wr * 64 + m * 16 + arow;
        int sl  = ((kk * 4 + hi) ^ (row & 7)) * 8;
        af[m] = *(bf16x8*)&Al[cur][row * 64 + sl];
      }
#pragma unroll
      for (int n = 0; n < 4; ++n) {
        int row = wc * 64 + n * 16 + arow;
        int sl  = ((kk * 4 + hi) ^ (row & 7)) * 8;
        bfr[n] = *(bf16x8*)&Bl[cur][row * 64 + sl];
      }
#pragma unroll
      for (int m = 0; m < 4; ++m)
#pragma unroll
        for (int n = 0; n < 4; ++n)
          acc[m][n] = MFMA16(af[m], bfr[n], acc[m][n]);
    }
    __builtin_amdgcn_s_setprio(0);

    if (t < 7) commit(cur ^ 1);
  }

  // Epilogue: bias + relu + oscale (+ Q row-mask zeroing), bf16 store.
#pragma unroll
  for (int n = 0; n < 4; ++n) {
    int col = nbase + wc * 64 + n * 16 + arow;
    float bsv = bias[col];
    int h = col >> 7, d = col & 127;
#pragma unroll
    for (int m = 0; m < 4; ++m) {
      int row0 = mbase + wr * 64 + m * 16 + hi * 4;
#pragma unroll
      for (int r = 0; r < 4; ++r) {
        float v = acc[m][n][r] + bsv;
        v = (v > 0.0f ? v : 0.0f) * oscale;
        int mm = row0 + r;
        int b = mm >> 11, s = mm & 2047;
        if (which == 0 && mask[b * 2048 + s] != 0) v = 0.0f;
        size_t bhoff = (size_t)(b * 4 + h) * (2048 * 128);
        int tt = s >> 6, kw_ = (s >> 5) & 1;
        if (which == 0) {
          dst[bhoff + (size_t)s * 128 + d] = (__bf16)v;
        } else if (which == 1) {
          int r5k = s & 31;
          int ds = d >> 4, hi3 = (d >> 3) & 1, j = d & 7;
          size_t unit = ((size_t)tt * 2 + kw_) * 8 + ds;
          dst[bhoff + unit * 512 + hi3 * 256 + r5k * 8 + j] = (__bf16)v;
        } else {
          int s2 = (s >> 4) & 1, hi3 = (s >> 3) & 1, j = s & 7;
          int dblk = d >> 5, r5 = d & 31;
          size_t unit = ((size_t)tt * 2 + kw_) * 8 + dblk * 2 + s2;
          dst[bhoff + unit * 512 + hi3 * 256 + r5 * 8 + j] = (__bf16)v;
        }
      }
    }
  }
}

// ---------------------------------------------------------------------------
// Flash attention, barrier-free main loop, K/V fragment-linear in global.
// 512 thr = 8 waves = 4 q-subtiles x 2 kv-halves (q=128/block): each K/V
// stream is amortized over 4x more q -> L2 read traffic 1GB -> 256MB.
// grid 256 = 8 XCD x (2 bh x 16 q-tiles). Pairwise kv-merge per q-subtile.
// ---------------------------------------------------------------------------
__global__ __launch_bounds__(512, 2) void attn_kernel(
    const __bf16* __restrict__ qh, const __bf16* __restrict__ kfr,
    const __bf16* __restrict__ vfr, const float* __restrict__ queries,
    float* __restrict__ out)
{
  __shared__ float Ll[4][32];
  __shared__ __align__(16) float Ob[4][64 * 68];

  const int tid  = threadIdx.x;
  const int lane = tid & 63;
  const int w    = tid >> 6;        // 0..7
  const int qw   = w >> 1;          // q-subtile 0..3
  const int kw   = w & 1;           // kv-half
  const int r5   = lane & 31;
  const int hi32 = lane >> 5;

  const int blk  = blockIdx.x;      // 0..255
  const int xcd  = blk & 7;
  const int rest = blk >> 3;        // 0..31
  const int bh   = xcd * 2 + (rest & 1);
  const int qt   = rest >> 1;       // 0..15
  const int b = bh >> 2, h = bh & 3;
  const int qbase = qt * 128 + qw * 32;

  const __bf16* qptr = qh  + (size_t)bh * 2048 * 128;
  const __bf16* kp   = kfr + (size_t)bh * 2048 * 128;
  const __bf16* vp   = vfr + (size_t)bh * 2048 * 128;

  bf16x8 qf[8];
#pragma unroll
  for (int ds = 0; ds < 8; ++ds)
    qf[ds] = *(const bf16x8*)&qptr[(size_t)(qbase + r5) * 128 + ds * 16 + hi32 * 8];

  float l_st = 0.f;
  f32x16 oacc[4] = {};
  bf16x8 kf[8], vfA[8], vfB[8];

  auto loadK = [&](int t) {
#pragma unroll
    for (int ds = 0; ds < 8; ++ds)
      kf[ds] = *(const bf16x8*)
          &kp[(((size_t)t * 2 + kw) * 8 + ds) * 512 + lane * 8];
  };
  auto loadV = [&](bf16x8 (&dstv)[8], int t) {
#pragma unroll
    for (int u = 0; u < 8; ++u)
      dstv[u] = *(const bf16x8*)
          &vp[(((size_t)t * 2 + kw) * 8 + u) * 512 + lane * 8];
  };

  auto body = [&](int t, bf16x8 (&vcur)[8]) {
    // QK^T swapped: S[kv][q=lane&31] (log2 domain, Q pre-scaled).
    f32x16 sacc = {};
    __builtin_amdgcn_s_setprio(1);
#pragma unroll
    for (int ds = 0; ds < 8; ++ds)
      sacc = MFMA32(kf[ds], qf[ds], sacc);
    __builtin_amdgcn_s_setprio(0);

    if (t + 1 < 32) loadK(t + 1);   // K prefetch: lands during softmax+PV

    // Fixed-reference softmax: P = exp2(s) (scores >= 0, bounded; masked
    // rows have Q==0 -> P==1 -> mean(V)). Tree-sum.
    float ps[16];
#pragma unroll
    for (int r = 0; r < 16; ++r) {
      ps[r] = __builtin_amdgcn_exp2f(sacc[r]);
      sacc[r] = ps[r];
    }
#pragma unroll
    for (int st = 1; st < 16; st <<= 1)
#pragma unroll
      for (int r = 0; r < 16; r += 2 * st)
        ps[r] += ps[r + st];
    l_st += ps[0];

    // P -> B-frags: bf16 pack pairs + permlane32_swap.
    unsigned pk[8];
#pragma unroll
    for (int g = 0; g < 8; ++g) {
      bf16x2 tp;
      tp[0] = (__bf16)sacc[2 * g];
      tp[1] = (__bf16)sacc[2 * g + 1];
      pk[g] = __builtin_bit_cast(unsigned, tp);
    }
    bf16x8 pf[2];
#pragma unroll
    for (int s = 0; s < 2; ++s) {
      unsigned a0 = pk[4 * s + 0], a1 = pk[4 * s + 1];
      unsigned b0 = pk[4 * s + 2], b1 = pk[4 * s + 3];
      asm("v_permlane32_swap_b32 %0, %1" : "+v"(a0), "+v"(b0));
      asm("v_permlane32_swap_b32 %0, %1" : "+v"(a1), "+v"(b1));
      union { unsigned u[4]; bf16x8 v; } pu;
      pu.u[0] = a0; pu.u[1] = a1; pu.u[2] = b0; pu.u[3] = b1;
      pf[s] = pu.v;
    }

    __builtin_amdgcn_s_setprio(1);
#pragma unroll
    for (int u = 0; u < 8; ++u)     // u = dblk*2 + s
      oacc[u >> 1] = MFMA32(vcur[u], pf[u & 1], oacc[u >> 1]);
    __builtin_amdgcn_s_setprio(0);

    if (t + 2 < 32) loadV(vcur, t + 2);  // V prefetch, 2 tiles ahead
  };

  loadK(0);
  loadV(vfA, 0);
  loadV(vfB, 1);

  for (int tt = 0; tt < 16; ++tt) {
    body(2 * tt, vfA);
    body(2 * tt + 1, vfB);
  }

  // ---- merge kv-halves per q-subtile (plain sums), then epilogue ----
  float l_tot = l_st + __shfl_xor(l_st, 32);

  if (kw == 1) {
    if (hi32 == 0) Ll[qw][r5] = l_tot;
    float* dstp = &Ob[qw][(size_t)lane * 68];
#pragma unroll
    for (int dblk = 0; dblk < 4; ++dblk)
      *(f32x16*)(dstp + dblk * 16) = oacc[dblk];
  }
  __syncthreads();

  if (kw == 0) {
    float l1 = Ll[qw][r5];
    float inv = 1.0f / (l_tot + l1);
    const float* src = &Ob[qw][(size_t)lane * 68];

    const int qq  = qt * 128 + qw * 32;
    const int qhi = qq >> 9;
    const int col = (qq & 511) + r5;
#pragma unroll
    for (int dblk = 0; dblk < 4; ++dblk) {
      f32x16 o1 = *(const f32x16*)(src + dblk * 16);
#pragma unroll
      for (int r = 0; r < 16; ++r) {
        int d = dblk * 32 + (r & 3) + 8 * (r >> 2) + 4 * hi32;
        int srow = h * 512 + d * 4 + qhi;
        size_t o = ((size_t)b * 2048 + srow) * 512 + col;
        out[o] = (oacc[dblk][r] + o1[r]) * inv + queries[o];
      }
    }
  }
}

extern "C" void kernel_launch(void* const* d_in, const int* in_sizes, int n_in,
                              void* d_out, int out_size, void* d_ws, size_t ws_size,
                              hipStream_t stream) {
  const float* queries = (const float*)d_in[0];
  const float* keys    = (const float*)d_in[1];
  const float* values  = (const float*)d_in[2];
  const int*   mask    = (const int*)d_in[3];
  const float* Wq = (const float*)d_in[4];
  const float* bq = (const float*)d_in[5];
  const float* Wk = (const float*)d_in[6];
  const float* bk = (const float*)d_in[7];
  const float* Wv = (const float*)d_in[8];
  const float* bv = (const float*)d_in[9];
  float* out = (float*)d_out;

  const size_t perX = (size_t)8192 * 512;
  __bf16* qhp = (__bf16*)d_ws;
  __bf16* khp = qhp + perX;
  __bf16* vtp = khp + perX;

  gemm_kernel<<<dim3(64, 4, 3), dim3(256), 0, stream>>>(
      queries, keys, values, Wq, Wk, Wv, bq, bk, bv, mask, qhp, khp, vtp);

  attn_kernel<<<dim3(256), dim3(512), 0, stream>>>(qhp, khp, vtp, queries, out);
}